// Round 1
// baseline (115.132 us; speedup 1.0000x reference)
//
#include <hip/hip_runtime.h>

#define BATCH 8192
#define FEAT_DIM 512
#define NUM_CLASSES 2048
#define ROWS_PER_BLOCK 4

// Seed output with the clip-of-masked-zeros term: (C-1)*1e-12.
// Also guarantees deterministic output across graph replays (harness does
// not re-poison d_out between replays; we fully re-init every call).
__global__ void center_loss_init(float* __restrict__ out) {
    out[0] = (float)(NUM_CLASSES - 1) * 1e-12f;
}

__global__ __launch_bounds__(256)
void center_loss_kernel(const float* __restrict__ features,
                        const float* __restrict__ centers,
                        const int* __restrict__ target,
                        float* __restrict__ out) {
    const int wave = threadIdx.x >> 6;          // 0..3
    const int lane = threadIdx.x & 63;          // 0..63
    const int row  = blockIdx.x * ROWS_PER_BLOCK + wave;
    if (row >= BATCH) return;

    const int t = target[row];

    const float4* __restrict__ fp =
        (const float4*)(features + (size_t)row * FEAT_DIM);
    const float4* __restrict__ cp =
        (const float4*)(centers + (size_t)t * FEAT_DIM);

    // 512 floats = 128 float4 per row; 64 lanes -> 2 float4 each.
    float acc = 0.0f;
#pragma unroll
    for (int k = 0; k < 2; ++k) {
        const float4 a = fp[lane + 64 * k];
        const float4 b = cp[lane + 64 * k];
        const float dx = a.x - b.x;
        const float dy = a.y - b.y;
        const float dz = a.z - b.z;
        const float dw = a.w - b.w;
        acc += dx * dx + dy * dy + dz * dz + dw * dw;
    }

    // 64-lane butterfly reduction.
#pragma unroll
    for (int off = 32; off > 0; off >>= 1)
        acc += __shfl_down(acc, off, 64);

    if (lane == 0) {
        const float d = acc < 1e-12f ? 1e-12f : acc;   // clip lower bound
        atomicAdd(out, d * (1.0f / (float)BATCH));
    }
}

extern "C" void kernel_launch(void* const* d_in, const int* in_sizes, int n_in,
                              void* d_out, int out_size, void* d_ws, size_t ws_size,
                              hipStream_t stream) {
    const float* features = (const float*)d_in[0];
    const float* centers  = (const float*)d_in[1];
    const int*   target   = (const int*)d_in[2];
    float* out = (float*)d_out;

    center_loss_init<<<1, 1, 0, stream>>>(out);

    const int grid = BATCH / ROWS_PER_BLOCK;   // 2048 blocks x 256 threads
    center_loss_kernel<<<grid, 256, 0, stream>>>(features, centers, target, out);
}

// Round 2
// 12.130 us; speedup vs baseline: 9.4912x; 9.4912x over previous
//
#include <hip/hip_runtime.h>

#define BATCH 8192
#define FEAT_DIM 512
#define NUM_CLASSES 2048

#define GRID1 1024
#define WAVES_PER_BLOCK 4
#define TOTAL_WAVES (GRID1 * WAVES_PER_BLOCK)     // 4096
#define ROWS_PER_WAVE (BATCH / TOTAL_WAVES)       // 2

// Stage 1: per-wave row distances -> per-block partial sums in d_ws.
// No atomics anywhere.
__global__ __launch_bounds__(256)
void center_loss_partial(const float* __restrict__ features,
                         const float* __restrict__ centers,
                         const int* __restrict__ target,
                         float* __restrict__ ws) {
    const int wave = threadIdx.x >> 6;      // 0..3
    const int lane = threadIdx.x & 63;      // 0..63
    const int wid  = blockIdx.x * WAVES_PER_BLOCK + wave;   // 0..4095

    float wsum = 0.0f;
#pragma unroll
    for (int r = 0; r < ROWS_PER_WAVE; ++r) {
        const int row = wid + r * TOTAL_WAVES;
        const int t = target[row];
        const float4* __restrict__ fp =
            (const float4*)(features + (size_t)row * FEAT_DIM);
        const float4* __restrict__ cp =
            (const float4*)(centers + (size_t)t * FEAT_DIM);

        // 128 float4 per row; 64 lanes -> 2 each. Issue all loads first (ILP).
        const float4 a0 = fp[lane];
        const float4 a1 = fp[lane + 64];
        const float4 b0 = cp[lane];
        const float4 b1 = cp[lane + 64];

        float acc;
        {
            const float dx0 = a0.x - b0.x, dy0 = a0.y - b0.y;
            const float dz0 = a0.z - b0.z, dw0 = a0.w - b0.w;
            const float dx1 = a1.x - b1.x, dy1 = a1.y - b1.y;
            const float dz1 = a1.z - b1.z, dw1 = a1.w - b1.w;
            acc = dx0 * dx0 + dy0 * dy0 + dz0 * dz0 + dw0 * dw0
                + dx1 * dx1 + dy1 * dy1 + dz1 * dz1 + dw1 * dw1;
        }

        // 64-lane butterfly reduction (all lanes end with the row sum).
#pragma unroll
        for (int off = 32; off > 0; off >>= 1)
            acc += __shfl_xor(acc, off, 64);

        // clip per row (matches reference's per-element clip on the diagonal)
        wsum += fminf(fmaxf(acc, 1e-12f), 1.0e12f);
    }

    __shared__ float s[WAVES_PER_BLOCK];
    if (lane == 0) s[wave] = wsum;
    __syncthreads();
    if (threadIdx.x == 0) {
        float b = 0.0f;
#pragma unroll
        for (int w = 0; w < WAVES_PER_BLOCK; ++w) b += s[w];
        ws[blockIdx.x] = b;
    }
}

// Stage 2: reduce GRID1 partials, scale, add the clip-of-masked-zeros
// constant, and fully overwrite out[0] (deterministic every call).
__global__ __launch_bounds__(256)
void center_loss_final(const float* __restrict__ ws, float* __restrict__ out) {
    const int tid  = threadIdx.x;
    const int wave = tid >> 6;
    const int lane = tid & 63;

    float acc = 0.0f;
    for (int i = tid; i < GRID1; i += 256) acc += ws[i];

#pragma unroll
    for (int off = 32; off > 0; off >>= 1)
        acc += __shfl_xor(acc, off, 64);

    __shared__ float s[4];
    if (lane == 0) s[wave] = acc;
    __syncthreads();
    if (tid == 0) {
        const float total = s[0] + s[1] + s[2] + s[3];
        out[0] = total * (1.0f / (float)BATCH)
               + (float)(NUM_CLASSES - 1) * 1e-12f;
    }
}

extern "C" void kernel_launch(void* const* d_in, const int* in_sizes, int n_in,
                              void* d_out, int out_size, void* d_ws, size_t ws_size,
                              hipStream_t stream) {
    const float* features = (const float*)d_in[0];
    const float* centers  = (const float*)d_in[1];
    const int*   target   = (const int*)d_in[2];
    float* out = (float*)d_out;
    float* ws  = (float*)d_ws;

    center_loss_partial<<<GRID1, 256, 0, stream>>>(features, centers, target, ws);
    center_loss_final<<<1, 256, 0, stream>>>(ws, out);
}

// Round 3
// 11.489 us; speedup vs baseline: 10.0212x; 1.0558x over previous
//
#include <hip/hip_runtime.h>

#define BATCH 8192
#define FEAT_DIM 512
#define NUM_CLASSES 2048

#define WAVES_PER_BLOCK 4
#define BLOCKS1 (BATCH / WAVES_PER_BLOCK)   // 2048 blocks, 1 row per wave

// Stage 1: one wave per row. No LDS, no __syncthreads, no atomics.
// Each wave writes its clipped squared distance to ws[row].
__global__ __launch_bounds__(256)
void center_loss_partial(const float* __restrict__ features,
                         const float* __restrict__ centers,
                         const int* __restrict__ target,
                         float* __restrict__ ws) {
    const int wave = threadIdx.x >> 6;      // 0..3
    const int lane = threadIdx.x & 63;      // 0..63
    const int row  = blockIdx.x * WAVES_PER_BLOCK + wave;   // 0..8191

    const int t = target[row];
    const float4* __restrict__ fp =
        (const float4*)(features + (size_t)row * FEAT_DIM);
    const float4* __restrict__ cp =
        (const float4*)(centers + (size_t)t * FEAT_DIM);

    // 128 float4 per row; 64 lanes -> 2 float4 from each matrix.
    // Issue all 4 loads before any math (max memory-level parallelism).
    const float4 a0 = fp[lane];
    const float4 a1 = fp[lane + 64];
    const float4 b0 = cp[lane];
    const float4 b1 = cp[lane + 64];

    const float dx0 = a0.x - b0.x, dy0 = a0.y - b0.y;
    const float dz0 = a0.z - b0.z, dw0 = a0.w - b0.w;
    const float dx1 = a1.x - b1.x, dy1 = a1.y - b1.y;
    const float dz1 = a1.z - b1.z, dw1 = a1.w - b1.w;
    float acc = dx0 * dx0 + dy0 * dy0 + dz0 * dz0 + dw0 * dw0
              + dx1 * dx1 + dy1 * dy1 + dz1 * dz1 + dw1 * dw1;

    // 64-lane butterfly reduction.
#pragma unroll
    for (int off = 32; off > 0; off >>= 1)
        acc += __shfl_xor(acc, off, 64);

    if (lane == 0)
        ws[row] = fminf(fmaxf(acc, 1e-12f), 1.0e12f);   // per-element clip
}

// Stage 2: sum 8192 partials (read as 2048 float4), scale, add the
// clip-of-masked-zeros constant, fully overwrite out[0] every call.
__global__ __launch_bounds__(256)
void center_loss_final(const float4* __restrict__ ws, float* __restrict__ out) {
    const int tid  = threadIdx.x;
    const int wave = tid >> 6;
    const int lane = tid & 63;

    float acc = 0.0f;
#pragma unroll
    for (int i = 0; i < 8; ++i) {
        const float4 v = ws[tid + 256 * i];   // coalesced, 2048 float4 total
        acc += (v.x + v.y) + (v.z + v.w);
    }

#pragma unroll
    for (int off = 32; off > 0; off >>= 1)
        acc += __shfl_xor(acc, off, 64);

    __shared__ float s[4];
    if (lane == 0) s[wave] = acc;
    __syncthreads();
    if (tid == 0) {
        const float total = (s[0] + s[1]) + (s[2] + s[3]);
        out[0] = total * (1.0f / (float)BATCH)
               + (float)(NUM_CLASSES - 1) * 1e-12f;
    }
}

extern "C" void kernel_launch(void* const* d_in, const int* in_sizes, int n_in,
                              void* d_out, int out_size, void* d_ws, size_t ws_size,
                              hipStream_t stream) {
    const float* features = (const float*)d_in[0];
    const float* centers  = (const float*)d_in[1];
    const int*   target   = (const int*)d_in[2];
    float* out = (float*)d_out;
    float* ws  = (float*)d_ws;

    center_loss_partial<<<BLOCKS1, 256, 0, stream>>>(features, centers, target, ws);
    center_loss_final<<<1, 256, 0, stream>>>((const float4*)ws, out);
}